// Round 12
// baseline (224.978 us; speedup 1.0000x reference)
//
#include <hip/hip_runtime.h>
#include <hip/hip_bf16.h>

#define NODES_N 100000
#define EDGES_E 1600000
#define GRAPHS_G 64

// binned CSR build geometry
#define BIN_SHIFT 8
#define BIN_NODES 256                 // nodes per bin
#define NBINS 391                     // ceil(100000/256)
#define NB1 512                       // phase-1 blocks
#define EPB1 3125                     // ceil(E/NB1)

typedef unsigned int uint;
typedef unsigned short ushort;
typedef __attribute__((ext_vector_type(8))) short bf16x8;
typedef __attribute__((ext_vector_type(4))) float f32x4;

// ---------------- helpers ----------------

__device__ inline uint pack_bf2(float lo, float hi) {
    __hip_bfloat162 h2 = __float22bfloat162_rn(make_float2(lo, hi));
    return *reinterpret_cast<uint*>(&h2);
}

__device__ inline void acc_bf2(uint w, float& a0, float& a1) {
    a0 += __uint_as_float(w << 16);
    a1 += __uint_as_float(w & 0xffff0000u);
}

__device__ inline ushort f2bf(float v) {
    __hip_bfloat16 b = __float2bfloat16(v);
    return *reinterpret_cast<ushort*>(&b);
}

// ---------------- W fragment pack + zero sums/cnts/dhist/dcur ----------------

__device__ inline void pack_w_one(const float* W, ushort* Wf, int gid, int KS) {
    int j = gid & 7, l = (gid >> 3) & 63, f = gid >> 9;
    int nt = f / KS, ks = f - nt * KS;
    int k = ks * 32 + ((l >> 4) & 3) * 8 + j;
    int n = nt * 16 + (l & 15);
    Wf[gid] = f2bf(W[k * 128 + n]);
}

#define NZERO (GRAPHS_G * 128 + GRAPHS_G + 128)   // sums + cnts + dhist(64) + dcur(64)

__global__ void pack_w_zero_k(const float* __restrict__ W1, ushort* __restrict__ W1f,
                              const float* __restrict__ W2, ushort* __restrict__ W2f,
                              float* __restrict__ zf) {
    int gid = blockIdx.x * 256 + threadIdx.x;
    if (gid < 8192) pack_w_one(W1, W1f, gid, 2);                       // K=64
    else if (gid < 24576) pack_w_one(W2, W2f, gid - 8192, 4);          // K=128
    else {
        int i = gid - 24576;
        if (i < NZERO) zf[i] = 0.f;
    }
}

// ---------------- binned CSR build (no global atomic-returns in bulk paths) ----------------

__global__ __launch_bounds__(256) void p1_hist_k(const int* __restrict__ dst,
                                                 int* __restrict__ hist_t) {
    __shared__ int h[NBINS];
    for (int i = threadIdx.x; i < NBINS; i += 256) h[i] = 0;
    __syncthreads();
    int b = blockIdx.x;
    int e0 = b * EPB1, e1 = min(EDGES_E, e0 + EPB1);
    for (int e = e0 + threadIdx.x; e < e1; e += 256)
        atomicAdd(&h[dst[e] >> BIN_SHIFT], 1);
    __syncthreads();
    for (int i = threadIdx.x; i < NBINS; i += 256)
        hist_t[i * NB1 + b] = h[i];     // bin-major for the per-bin scan
}

__global__ __launch_bounds__(256) void p1_scanbins_k(int* __restrict__ hist_t,
                                                     int* __restrict__ bintot) {
    __shared__ int sd[256];
    __shared__ int carry;
    int bin = blockIdx.x, t = threadIdx.x;
    if (t == 0) carry = 0;
    __syncthreads();
    int* row = hist_t + bin * NB1;
    for (int base = 0; base < NB1; base += 256) {
        int v = row[base + t];
        sd[t] = v; __syncthreads();
        for (int o = 1; o < 256; o <<= 1) {
            int x = (t >= o) ? sd[t - o] : 0;
            __syncthreads();
            sd[t] += x;
            __syncthreads();
        }
        row[base + t] = carry + sd[t] - v;   // exclusive within bin
        __syncthreads();
        if (t == 255) carry += sd[255];
        __syncthreads();
    }
    if (t == 0) bintot[bin] = carry;
}

__global__ __launch_bounds__(1024) void binstart_k(const int* __restrict__ bintot,
                                                   int* __restrict__ binstart,
                                                   int* __restrict__ rowptr) {
    __shared__ int sd[1024];
    int t = threadIdx.x;
    int v = (t < NBINS) ? bintot[t] : 0;
    sd[t] = v; __syncthreads();
    for (int o = 1; o < 1024; o <<= 1) {
        int x = (t >= o) ? sd[t - o] : 0;
        __syncthreads();
        sd[t] += x;
        __syncthreads();
    }
    if (t < NBINS) binstart[t] = sd[t] - v;
    if (t == 0) { binstart[NBINS] = EDGES_E; rowptr[NODES_N] = EDGES_E; }
}

__global__ __launch_bounds__(256) void p1_scatter_k(const int* __restrict__ src,
                                                    const int* __restrict__ dst,
                                                    const int* __restrict__ hist_t,
                                                    const int* __restrict__ binstart,
                                                    uint* __restrict__ pairs) {
    __shared__ int cur[NBINS];
    int b = blockIdx.x;
    for (int i = threadIdx.x; i < NBINS; i += 256)
        cur[i] = binstart[i] + hist_t[i * NB1 + b];
    __syncthreads();
    int e0 = b * EPB1, e1 = min(EDGES_E, e0 + EPB1);
    for (int e = e0 + threadIdx.x; e < e1; e += 256) {
        int d = dst[e];
        int pos = atomicAdd(&cur[d >> BIN_SHIFT], 1);
        pairs[pos] = ((uint)src[e] << BIN_SHIFT) | (uint)(d & (BIN_NODES - 1));
    }
}

// phase 2: per bin (256 nodes), build CSR rowptr/colidx + dinv + scaled bf16 x~
// + accumulate the global 64-bucket degree histogram (for the scheduling perm)
__global__ __launch_bounds__(256) void p2_build_k(const uint* __restrict__ pairs,
                                                  const int* __restrict__ binstart,
                                                  const float* __restrict__ x,
                                                  int* __restrict__ colidx,
                                                  int* __restrict__ rowptr,
                                                  float* __restrict__ dinv,
                                                  uint* __restrict__ xt,
                                                  int* __restrict__ dhist) {
    __shared__ int h[BIN_NODES];
    __shared__ int off[BIN_NODES];
    __shared__ int cur[BIN_NODES];
    __shared__ float ldv[BIN_NODES];
    __shared__ int dgh[64];
    int bin = blockIdx.x, t = threadIdx.x;
    int node0 = bin << BIN_SHIFT;
    h[t] = 0;
    if (t < 64) dgh[t] = 0;
    __syncthreads();
    int e0 = binstart[bin], e1 = binstart[bin + 1];
    for (int e = e0 + t; e < e1; e += 256)
        atomicAdd(&h[pairs[e] & (BIN_NODES - 1)], 1);
    __syncthreads();
    off[t] = h[t];
    __syncthreads();
    for (int o = 1; o < BIN_NODES; o <<= 1) {
        int x2 = (t >= o) ? off[t - o] : 0;
        __syncthreads();
        off[t] += x2;
        __syncthreads();
    }
    {
        int excl = off[t] - h[t];
        cur[t] = e0 + excl;
        float dv = rsqrtf((float)h[t] + 1.0f);
        ldv[t] = dv;
        int node = node0 + t;
        if (node < NODES_N) {
            rowptr[node] = e0 + excl;
            dinv[node] = dv;
            atomicAdd(&dgh[min(h[t], 63)], 1);
        }
    }
    __syncthreads();
    for (int e = e0 + t; e < e1; e += 256) {
        uint p = pairs[e];
        int pos = atomicAdd(&cur[p & (BIN_NODES - 1)], 1);
        colidx[pos] = (int)(p >> BIN_SHIFT);
    }
    // fused scale_x: x~ = bf16(x * dinv) for this bin's nodes
    int nmax = min(NODES_N - node0, BIN_NODES);
    for (int i = t; i < nmax * 16; i += 256) {
        int nl = i >> 4, c = i & 15;
        int node = node0 + nl;
        float dv = ldv[nl];
        float4 v = *(const float4*)&x[(size_t)node * 64 + c * 4];
        uint2 o = make_uint2(pack_bf2(v.x * dv, v.y * dv), pack_bf2(v.z * dv, v.w * dv));
        *(uint2*)&xt[(size_t)node * 32 + c * 2] = o;
    }
    __syncthreads();
    if (t < 64 && dgh[t] > 0) atomicAdd(&dhist[t], dgh[t]);
}

// ---------------- degree-bucket permutation (equalize per-wave edge trips) ----------------
// Every block redundantly scans the 64-bucket histogram; claims a per-(block,bucket)
// range with ONE atomic-return per bucket (hierarchical: 25K returns total, spread);
// local rank via LDS atomics. perm is a valid permutation of [0,N).

__global__ __launch_bounds__(256) void perm_k(const int* __restrict__ rowptr,
                                              const int* __restrict__ dhist,
                                              int* __restrict__ dcur,
                                              int* __restrict__ perm) {
    __shared__ int dh[64], dstart[64], dbase[64], dloc[64];
    int b = blockIdx.x, t = threadIdx.x;
    if (t < 64) { dh[t] = 0; dloc[t] = 0; }
    __syncthreads();
    int node = (b << BIN_SHIFT) + t;
    bool act = node < NODES_N;
    int bk = 0;
    if (act) {
        int deg = rowptr[node + 1] - rowptr[node];
        bk = min(deg, 63);
        atomicAdd(&dh[bk], 1);
    }
    __syncthreads();
    if (t < 64) dstart[t] = dhist[t];
    __syncthreads();
    for (int o = 1; o < 64; o <<= 1) {
        int x = (t >= o && t < 64) ? dstart[t - o] : 0;
        __syncthreads();
        if (t < 64) dstart[t] += x;
        __syncthreads();
    }
    if (t < 64) {
        int excl = dstart[t] - dhist[t];
        dbase[t] = (dh[t] > 0) ? excl + atomicAdd(&dcur[t], dh[t]) : 0;
    }
    __syncthreads();
    if (act) {
        int r = atomicAdd(&dloc[bk], 1);
        perm[dbase[bk] + r] = node;
    }
}

// ---------------- gather 64-dim bf16 -> bf16 sum (unroll-8, degree-sorted order) ----------------

__global__ __launch_bounds__(256) void gather64_k(const uint* __restrict__ xt,
                                                  const int* __restrict__ rowptr,
                                                  const int* __restrict__ colidx,
                                                  const int* __restrict__ perm,
                                                  uint* __restrict__ st, int n) {
    int lane = threadIdx.x & 7;
    int local = threadIdx.x >> 3;   // 32 nodes/block
    int co = lane * 4;
    int idx = blockIdx.x * 32 + local;
    if (idx >= n) return;
    int node = perm[idx];
    float a0=0,a1=0,a2=0,a3=0,a4=0,a5=0,a6=0,a7=0;
    uint4 v = *(const uint4*)&xt[(size_t)node * 32 + co];
    acc_bf2(v.x, a0, a1); acc_bf2(v.y, a2, a3);
    acc_bf2(v.z, a4, a5); acc_bf2(v.w, a6, a7);
    int beg = rowptr[node], end = rowptr[node + 1];
    int e = beg;
    for (; e + 7 < end; e += 8) {
        int i0 = colidx[e],   i1 = colidx[e+1], i2 = colidx[e+2], i3 = colidx[e+3];
        int i4 = colidx[e+4], i5 = colidx[e+5], i6 = colidx[e+6], i7 = colidx[e+7];
        uint4 w0 = *(const uint4*)&xt[(size_t)i0 * 32 + co];
        uint4 w1 = *(const uint4*)&xt[(size_t)i1 * 32 + co];
        uint4 w2 = *(const uint4*)&xt[(size_t)i2 * 32 + co];
        uint4 w3 = *(const uint4*)&xt[(size_t)i3 * 32 + co];
        uint4 w4 = *(const uint4*)&xt[(size_t)i4 * 32 + co];
        uint4 w5 = *(const uint4*)&xt[(size_t)i5 * 32 + co];
        uint4 w6 = *(const uint4*)&xt[(size_t)i6 * 32 + co];
        uint4 w7 = *(const uint4*)&xt[(size_t)i7 * 32 + co];
        acc_bf2(w0.x,a0,a1); acc_bf2(w0.y,a2,a3); acc_bf2(w0.z,a4,a5); acc_bf2(w0.w,a6,a7);
        acc_bf2(w1.x,a0,a1); acc_bf2(w1.y,a2,a3); acc_bf2(w1.z,a4,a5); acc_bf2(w1.w,a6,a7);
        acc_bf2(w2.x,a0,a1); acc_bf2(w2.y,a2,a3); acc_bf2(w2.z,a4,a5); acc_bf2(w2.w,a6,a7);
        acc_bf2(w3.x,a0,a1); acc_bf2(w3.y,a2,a3); acc_bf2(w3.z,a4,a5); acc_bf2(w3.w,a6,a7);
        acc_bf2(w4.x,a0,a1); acc_bf2(w4.y,a2,a3); acc_bf2(w4.z,a4,a5); acc_bf2(w4.w,a6,a7);
        acc_bf2(w5.x,a0,a1); acc_bf2(w5.y,a2,a3); acc_bf2(w5.z,a4,a5); acc_bf2(w5.w,a6,a7);
        acc_bf2(w6.x,a0,a1); acc_bf2(w6.y,a2,a3); acc_bf2(w6.z,a4,a5); acc_bf2(w6.w,a6,a7);
        acc_bf2(w7.x,a0,a1); acc_bf2(w7.y,a2,a3); acc_bf2(w7.z,a4,a5); acc_bf2(w7.w,a6,a7);
    }
    for (; e + 3 < end; e += 4) {
        int i0 = colidx[e], i1 = colidx[e+1], i2 = colidx[e+2], i3 = colidx[e+3];
        uint4 w0 = *(const uint4*)&xt[(size_t)i0 * 32 + co];
        uint4 w1 = *(const uint4*)&xt[(size_t)i1 * 32 + co];
        uint4 w2 = *(const uint4*)&xt[(size_t)i2 * 32 + co];
        uint4 w3 = *(const uint4*)&xt[(size_t)i3 * 32 + co];
        acc_bf2(w0.x,a0,a1); acc_bf2(w0.y,a2,a3); acc_bf2(w0.z,a4,a5); acc_bf2(w0.w,a6,a7);
        acc_bf2(w1.x,a0,a1); acc_bf2(w1.y,a2,a3); acc_bf2(w1.z,a4,a5); acc_bf2(w1.w,a6,a7);
        acc_bf2(w2.x,a0,a1); acc_bf2(w2.y,a2,a3); acc_bf2(w2.z,a4,a5); acc_bf2(w2.w,a6,a7);
        acc_bf2(w3.x,a0,a1); acc_bf2(w3.y,a2,a3); acc_bf2(w3.z,a4,a5); acc_bf2(w3.w,a6,a7);
    }
    for (; e < end; e++) {
        uint4 w0 = *(const uint4*)&xt[(size_t)colidx[e] * 32 + co];
        acc_bf2(w0.x,a0,a1); acc_bf2(w0.y,a2,a3); acc_bf2(w0.z,a4,a5); acc_bf2(w0.w,a6,a7);
    }
    uint4 o;
    o.x = pack_bf2(a0, a1);
    o.y = pack_bf2(a2, a3);
    o.z = pack_bf2(a4, a5);
    o.w = pack_bf2(a6, a7);
    *(uint4*)&st[(size_t)node * 32 + co] = o;
}

// ---------------- dual MFMA GEMM: h2' = bf16( dinv * ( relu(dinv*(s~@W1)+b1) @ W2 ) ) ----------------
// C/D layout (HW-verified): col = lane&15, row = (lane>>4)*4 + reg.

__global__ __launch_bounds__(256) void gemm_dual_k(const ushort* __restrict__ A,
                                                   const ushort* __restrict__ W1f,
                                                   const ushort* __restrict__ W2f,
                                                   const float* __restrict__ dinv,
                                                   const float* __restrict__ b1,
                                                   ushort* __restrict__ h2p, int n) {
    __shared__ ushort hl[4][16][132];
    int wave = threadIdx.x >> 6;
    int lane = threadIdx.x & 63;
    int row0 = (blockIdx.x * 4 + wave) * 16;
    if (row0 >= n) return;
    int m = lane & 15, g = lane >> 4;
    int arow = min(row0 + m, n - 1);

    // GEMM1: K=64
    const ushort* ab = &A[(size_t)arow * 64 + g * 8];
    bf16x8 a0 = *reinterpret_cast<const bf16x8*>(ab);
    bf16x8 a1 = *reinterpret_cast<const bf16x8*>(ab + 32);
    f32x4 acc[8];
#pragma unroll
    for (int nt = 0; nt < 8; nt++) {
        acc[nt] = (f32x4){0.f, 0.f, 0.f, 0.f};
        bf16x8 w0 = *reinterpret_cast<const bf16x8*>(&W1f[((size_t)(nt * 2 + 0) * 64 + lane) * 8]);
        bf16x8 w1 = *reinterpret_cast<const bf16x8*>(&W1f[((size_t)(nt * 2 + 1) * 64 + lane) * 8]);
        acc[nt] = __builtin_amdgcn_mfma_f32_16x16x32_bf16(a0, w0, acc[nt], 0, 0, 0);
        acc[nt] = __builtin_amdgcn_mfma_f32_16x16x32_bf16(a1, w1, acc[nt], 0, 0, 0);
    }

    // epilogue 1 -> LDS (transposed store: [row][channel])
    int orow0 = row0 + g * 4;
#pragma unroll
    for (int r = 0; r < 4; r++) {
        float dvr = dinv[min(orow0 + r, n - 1)];
#pragma unroll
        for (int nt = 0; nt < 8; nt++) {
            float v = fmaxf(fmaf(dvr, acc[nt][r], b1[nt * 16 + m]), 0.f);
            hl[wave][g * 4 + r][nt * 16 + m] = f2bf(v);
        }
    }

    // A-fragments for K=128 from LDS
    bf16x8 hfrag[4];
#pragma unroll
    for (int ks = 0; ks < 4; ks++) {
        uint2 lo = *(const uint2*)&hl[wave][m][g * 8 + ks * 32];
        uint2 hi = *(const uint2*)&hl[wave][m][g * 8 + ks * 32 + 4];
        uint4 u = make_uint4(lo.x, lo.y, hi.x, hi.y);
        hfrag[ks] = *reinterpret_cast<bf16x8*>(&u);
    }

    // GEMM2: K=128
    f32x4 acc2[8];
#pragma unroll
    for (int nt = 0; nt < 8; nt++) {
        acc2[nt] = (f32x4){0.f, 0.f, 0.f, 0.f};
#pragma unroll
        for (int ks = 0; ks < 4; ks++) {
            bf16x8 w = *reinterpret_cast<const bf16x8*>(&W2f[((size_t)(nt * 4 + ks) * 64 + lane) * 8]);
            acc2[nt] = __builtin_amdgcn_mfma_f32_16x16x32_bf16(hfrag[ks], w, acc2[nt], 0, 0, 0);
        }
    }

    // epilogue 2: h2' = bf16(dinv * acc2)
#pragma unroll
    for (int r = 0; r < 4; r++) {
        int row = orow0 + r;
        if (row < n) {
            float dvr = dinv[row];
#pragma unroll
            for (int nt = 0; nt < 8; nt++)
                h2p[(size_t)row * 128 + nt * 16 + m] = f2bf(acc2[nt][r] * dvr);
        }
    }
}

// ---------------- gather 128-dim, pass P=blockIdx.y (unroll-8, degree-sorted order) ----------------

__global__ __launch_bounds__(256) void gather128_k(const uint* __restrict__ hp,
                                                   const int* __restrict__ rowptr,
                                                   const int* __restrict__ colidx,
                                                   const int* __restrict__ perm,
                                                   const float* __restrict__ dinv,
                                                   const float* __restrict__ bias,
                                                   uint* __restrict__ h2b, int n) {
    int P = blockIdx.y;
    int lane = threadIdx.x & 7;
    int local = threadIdx.x >> 3;   // 32 nodes/block
    int co = P * 32 + lane * 4;     // uint offset in row of 64 uints
    int idx = blockIdx.x * 32 + local;
    if (idx >= n) return;
    int node = perm[idx];
    float a0=0,a1=0,a2=0,a3=0,a4=0,a5=0,a6=0,a7=0;
    uint4 v = *(const uint4*)&hp[(size_t)node * 64 + co];
    acc_bf2(v.x, a0, a1); acc_bf2(v.y, a2, a3);
    acc_bf2(v.z, a4, a5); acc_bf2(v.w, a6, a7);
    int beg = rowptr[node], end = rowptr[node + 1];
    int e = beg;
    for (; e + 7 < end; e += 8) {
        int i0 = colidx[e],   i1 = colidx[e+1], i2 = colidx[e+2], i3 = colidx[e+3];
        int i4 = colidx[e+4], i5 = colidx[e+5], i6 = colidx[e+6], i7 = colidx[e+7];
        uint4 w0 = *(const uint4*)&hp[(size_t)i0 * 64 + co];
        uint4 w1 = *(const uint4*)&hp[(size_t)i1 * 64 + co];
        uint4 w2 = *(const uint4*)&hp[(size_t)i2 * 64 + co];
        uint4 w3 = *(const uint4*)&hp[(size_t)i3 * 64 + co];
        uint4 w4 = *(const uint4*)&hp[(size_t)i4 * 64 + co];
        uint4 w5 = *(const uint4*)&hp[(size_t)i5 * 64 + co];
        uint4 w6 = *(const uint4*)&hp[(size_t)i6 * 64 + co];
        uint4 w7 = *(const uint4*)&hp[(size_t)i7 * 64 + co];
        acc_bf2(w0.x,a0,a1); acc_bf2(w0.y,a2,a3); acc_bf2(w0.z,a4,a5); acc_bf2(w0.w,a6,a7);
        acc_bf2(w1.x,a0,a1); acc_bf2(w1.y,a2,a3); acc_bf2(w1.z,a4,a5); acc_bf2(w1.w,a6,a7);
        acc_bf2(w2.x,a0,a1); acc_bf2(w2.y,a2,a3); acc_bf2(w2.z,a4,a5); acc_bf2(w2.w,a6,a7);
        acc_bf2(w3.x,a0,a1); acc_bf2(w3.y,a2,a3); acc_bf2(w3.z,a4,a5); acc_bf2(w3.w,a6,a7);
        acc_bf2(w4.x,a0,a1); acc_bf2(w4.y,a2,a3); acc_bf2(w4.z,a4,a5); acc_bf2(w4.w,a6,a7);
        acc_bf2(w5.x,a0,a1); acc_bf2(w5.y,a2,a3); acc_bf2(w5.z,a4,a5); acc_bf2(w5.w,a6,a7);
        acc_bf2(w6.x,a0,a1); acc_bf2(w6.y,a2,a3); acc_bf2(w6.z,a4,a5); acc_bf2(w6.w,a6,a7);
        acc_bf2(w7.x,a0,a1); acc_bf2(w7.y,a2,a3); acc_bf2(w7.z,a4,a5); acc_bf2(w7.w,a6,a7);
    }
    for (; e + 3 < end; e += 4) {
        int i0 = colidx[e], i1 = colidx[e+1], i2 = colidx[e+2], i3 = colidx[e+3];
        uint4 w0 = *(const uint4*)&hp[(size_t)i0 * 64 + co];
        uint4 w1 = *(const uint4*)&hp[(size_t)i1 * 64 + co];
        uint4 w2 = *(const uint4*)&hp[(size_t)i2 * 64 + co];
        uint4 w3 = *(const uint4*)&hp[(size_t)i3 * 64 + co];
        acc_bf2(w0.x,a0,a1); acc_bf2(w0.y,a2,a3); acc_bf2(w0.z,a4,a5); acc_bf2(w0.w,a6,a7);
        acc_bf2(w1.x,a0,a1); acc_bf2(w1.y,a2,a3); acc_bf2(w1.z,a4,a5); acc_bf2(w1.w,a6,a7);
        acc_bf2(w2.x,a0,a1); acc_bf2(w2.y,a2,a3); acc_bf2(w2.z,a4,a5); acc_bf2(w2.w,a6,a7);
        acc_bf2(w3.x,a0,a1); acc_bf2(w3.y,a2,a3); acc_bf2(w3.z,a4,a5); acc_bf2(w3.w,a6,a7);
    }
    for (; e < end; e++) {
        uint4 w0 = *(const uint4*)&hp[(size_t)colidx[e] * 64 + co];
        acc_bf2(w0.x,a0,a1); acc_bf2(w0.y,a2,a3); acc_bf2(w0.z,a4,a5); acc_bf2(w0.w,a6,a7);
    }
    float dv = dinv[node];
    int jb = P * 64 + lane * 8;
    float4 b0 = *(const float4*)&bias[jb];
    float4 b1 = *(const float4*)&bias[jb + 4];
    float o0 = fmaxf(fmaf(dv, a0, b0.x), 0.f);
    float o1 = fmaxf(fmaf(dv, a1, b0.y), 0.f);
    float o2 = fmaxf(fmaf(dv, a2, b0.z), 0.f);
    float o3 = fmaxf(fmaf(dv, a3, b0.w), 0.f);
    float o4 = fmaxf(fmaf(dv, a4, b1.x), 0.f);
    float o5 = fmaxf(fmaf(dv, a5, b1.y), 0.f);
    float o6 = fmaxf(fmaf(dv, a6, b1.z), 0.f);
    float o7 = fmaxf(fmaf(dv, a7, b1.w), 0.f);
    uint4 ov;
    ov.x = pack_bf2(o0, o1);
    ov.y = pack_bf2(o2, o3);
    ov.z = pack_bf2(o4, o5);
    ov.w = pack_bf2(o6, o7);
    *(uint4*)&h2b[(size_t)node * 64 + co] = ov;
}

// ---------------- pool (bf16 input) ----------------

__global__ __launch_bounds__(128) void pool_k(const uint* __restrict__ h2b,
                                              const int* __restrict__ batch, int n,
                                              float* __restrict__ sums, float* __restrict__ cnts) {
    int j = threadIdx.x;             // channel 0..127
    int wj = j >> 1;                 // uint word
    int hi = j & 1;
    int chunk = (n + gridDim.x - 1) / gridDim.x;
    int i0 = blockIdx.x * chunk;
    int i1 = min(n, i0 + chunk);
    if (i0 >= n) return;
    int cur = batch[i0];
    float acc = 0.f;
    int cnt = 0;
    for (int i = i0; i < i1; i++) {
        int g = batch[i];
        if (g != cur) {
            atomicAdd(&sums[cur * 128 + j], acc);
            if (j == 0) atomicAdd(&cnts[cur], (float)cnt);
            acc = 0.f; cnt = 0; cur = g;
        }
        uint w = h2b[(size_t)i * 64 + wj];
        acc += __uint_as_float(hi ? (w & 0xffff0000u) : (w << 16));
        cnt++;
    }
    atomicAdd(&sums[cur * 128 + j], acc);
    if (j == 0) atomicAdd(&cnts[cur], (float)cnt);
}

// ---------------- MLP head ----------------

__global__ __launch_bounds__(64) void mlp_k(const float* __restrict__ sums, const float* __restrict__ cnts,
                                            const float* __restrict__ Wl1, const float* __restrict__ bl1,
                                            const float* __restrict__ Wl2, const float* __restrict__ bl2,
                                            float* __restrict__ out) {
    __shared__ float pooled[128];
    __shared__ float hidden[64];
    int g = blockIdx.x, t = threadIdx.x;
    float c = fmaxf(cnts[g], 1.0f);
    pooled[t]      = sums[g * 128 + t] / c;
    pooled[t + 64] = sums[g * 128 + 64 + t] / c;
    __syncthreads();
    float a = bl1[t];
#pragma unroll 4
    for (int cc = 0; cc < 128; cc++) a = fmaf(pooled[cc], Wl1[cc * 64 + t], a);
    hidden[t] = fmaxf(a, 0.f);
    __syncthreads();
    if (t < 10) {
        float o = bl2[t];
#pragma unroll 8
        for (int jj = 0; jj < 64; jj++) o = fmaf(hidden[jj], Wl2[jj * 10 + t], o);
        out[g * 10 + t] = o;
    }
}

// ---------------- launch ----------------

extern "C" void kernel_launch(void* const* d_in, const int* in_sizes, int n_in,
                              void* d_out, int out_size, void* d_ws, size_t ws_size,
                              hipStream_t stream) {
    const float* x    = (const float*)d_in[0];
    const int*   src  = (const int*)d_in[1];
    const int*   dst  = (const int*)d_in[2];
    const int*   batch= (const int*)d_in[3];
    const float* W1   = (const float*)d_in[4];
    const float* b1   = (const float*)d_in[5];
    const float* W2   = (const float*)d_in[6];
    const float* b2   = (const float*)d_in[7];
    const float* Wl1  = (const float*)d_in[8];
    const float* bl1  = (const float*)d_in[9];
    const float* Wl2  = (const float*)d_in[10];
    const float* bl2  = (const float*)d_in[11];
    float* out = (float*)d_out;

    const int N = NODES_N;

    size_t off = 0;
    auto take = [&](size_t bytes) { size_t o = off; off = (off + bytes + 255) & ~(size_t)255; return o; };
    char* ws = (char*)d_ws;
    uint*   h2p  = (uint*)(ws + take((size_t)N * 128 * 2));     // h2' bf16 [N,128] as uint[N,64]
    uint*   h2b  = (uint*)(ws + take((size_t)N * 128 * 2));     // h2 bf16 [N,128] as uint[N,64]
    // pairs (4B packed) and s~ (gather64 output) never coexist: share a 12.8 MB region
    size_t  shbytes = (size_t)N * 64 * 2;                       // 12.8 MB >= E*4 (6.4 MB)
    char*   shreg = ws + take(shbytes);
    uint*   pairs = (uint*)shreg;
    uint*   stil  = (uint*)shreg;                               // s~ bf16 [N,64] as uint[N,32]
    uint*   xt   = (uint*)(ws + take((size_t)N * 64 * 2));      // x~ bf16 [N,64]
    float*  dinv = (float*)(ws + take((size_t)N * 4));
    ushort* W1f  = (ushort*)(ws + take((size_t)64 * 128 * 2));
    ushort* W2f  = (ushort*)(ws + take((size_t)128 * 128 * 2));
    size_t zbytes = (size_t)NZERO * 4;
    char*  zbase  = ws + take(zbytes);
    float* sums   = (float*)zbase;
    float* cnts   = (float*)(zbase + (size_t)GRAPHS_G * 128 * 4);
    int*   dhist  = (int*)(zbase + (size_t)(GRAPHS_G * 128 + GRAPHS_G) * 4);
    int*   dcur   = dhist + 64;
    int*   rowptr = (int*)(ws + take((size_t)(N + 1) * 4));
    int*   colidx = (int*)(ws + take((size_t)EDGES_E * 4));
    int*   perm   = (int*)(ws + take((size_t)N * 4));
    int*   hist_t = (int*)(ws + take((size_t)NBINS * NB1 * 4));
    int*   bintot = (int*)(ws + take((size_t)NBINS * 4));
    int*   binstart = (int*)(ws + take((size_t)(NBINS + 1) * 4));
    (void)ws_size; (void)in_sizes; (void)n_in; (void)out_size;

    // weight packing + zeroing of sums/cnts/dhist/dcur (replaces hipMemsetAsync)
    pack_w_zero_k<<<(24576 + NZERO + 255) / 256, 256, 0, stream>>>(W1, W1f, W2, W2f, sums);

    // binned CSR build — no global atomic-returns in bulk paths
    p1_hist_k<<<NB1, 256, 0, stream>>>(dst, hist_t);
    p1_scanbins_k<<<NBINS, 256, 0, stream>>>(hist_t, bintot);
    binstart_k<<<1, 1024, 0, stream>>>(bintot, binstart, rowptr);
    p1_scatter_k<<<NB1, 256, 0, stream>>>(src, dst, hist_t, binstart, pairs);
    p2_build_k<<<NBINS, 256, 0, stream>>>(pairs, binstart, x, colidx, rowptr, dinv, xt, dhist);

    // degree-bucket permutation (scheduling only; outputs bit-identical)
    perm_k<<<NBINS, 256, 0, stream>>>(rowptr, dhist, dcur, perm);

    // conv1 gather: s~ = xt[self] + sum xt[src] (degree-sorted wave assignment)
    int g32 = (N + 31) / 32;
    gather64_k<<<g32, 256, 0, stream>>>(xt, rowptr, colidx, perm, stil, N);

    // dual GEMM: h1 stays on-chip; h2' = bf16(dinv*(relu(dinv*(s~@W1)+b1)@W2))
    int gblk = (N + 63) / 64;
    gemm_dual_k<<<gblk, 256, 0, stream>>>((const ushort*)stil, W1f, W2f, dinv, b1, (ushort*)h2p, N);

    // conv2 gather: h2 = bf16(relu(dinv*(self+sum) + b2)), two channel-half passes in one launch
    gather128_k<<<dim3(g32, 2), 256, 0, stream>>>(h2p, rowptr, colidx, perm, dinv, b2, h2b, N);

    // pool + head
    pool_k<<<1024, 128, 0, stream>>>(h2b, batch, N, sums, cnts);
    mlp_k<<<GRAPHS_G, 64, 0, stream>>>(sums, cnts, Wl1, bl1, Wl2, bl2, out);
}

// Round 13
// 208.925 us; speedup vs baseline: 1.0768x; 1.0768x over previous
//
#include <hip/hip_runtime.h>
#include <hip/hip_bf16.h>

#define NODES_N 100000
#define EDGES_E 1600000
#define GRAPHS_G 64

// binned CSR build geometry
#define BIN_SHIFT 8
#define BIN_NODES 256                 // nodes per bin
#define NBINS 391                     // ceil(100000/256)
#define NB1 512                       // phase-1 blocks
#define EPB1 3125                     // ceil(E/NB1)

typedef unsigned int uint;
typedef unsigned short ushort;
typedef __attribute__((ext_vector_type(8))) short bf16x8;
typedef __attribute__((ext_vector_type(4))) float f32x4;

// ---------------- helpers ----------------

__device__ inline uint pack_bf2(float lo, float hi) {
    __hip_bfloat162 h2 = __float22bfloat162_rn(make_float2(lo, hi));
    return *reinterpret_cast<uint*>(&h2);
}

__device__ inline void acc_bf2(uint w, float& a0, float& a1) {
    a0 += __uint_as_float(w << 16);
    a1 += __uint_as_float(w & 0xffff0000u);
}

__device__ inline ushort f2bf(float v) {
    __hip_bfloat16 b = __float2bfloat16(v);
    return *reinterpret_cast<ushort*>(&b);
}

// ---------------- W fragment pack + zero sums/cnts (independent of CSR chain) ----------------

__device__ inline void pack_w_one(const float* W, ushort* Wf, int gid, int KS) {
    int j = gid & 7, l = (gid >> 3) & 63, f = gid >> 9;
    int nt = f / KS, ks = f - nt * KS;
    int k = ks * 32 + ((l >> 4) & 3) * 8 + j;
    int n = nt * 16 + (l & 15);
    Wf[gid] = f2bf(W[k * 128 + n]);
}

#define NZERO (GRAPHS_G * 128 + GRAPHS_G)   // sums + cnts

__global__ void pack_w_zero_k(const float* __restrict__ W1, ushort* __restrict__ W1f,
                              const float* __restrict__ W2, ushort* __restrict__ W2f,
                              float* __restrict__ zf) {
    int gid = blockIdx.x * 256 + threadIdx.x;
    if (gid < 8192) pack_w_one(W1, W1f, gid, 2);                       // K=64
    else if (gid < 24576) pack_w_one(W2, W2f, gid - 8192, 4);          // K=128
    else {
        int i = gid - 24576;
        if (i < NZERO) zf[i] = 0.f;
    }
}

// ---------------- binned CSR build (no global atomic-returns) ----------------

__global__ __launch_bounds__(256) void p1_hist_k(const int* __restrict__ dst,
                                                 int* __restrict__ hist_t) {
    __shared__ int h[NBINS];
    for (int i = threadIdx.x; i < NBINS; i += 256) h[i] = 0;
    __syncthreads();
    int b = blockIdx.x;
    int e0 = b * EPB1, e1 = min(EDGES_E, e0 + EPB1);
    for (int e = e0 + threadIdx.x; e < e1; e += 256)
        atomicAdd(&h[dst[e] >> BIN_SHIFT], 1);
    __syncthreads();
    for (int i = threadIdx.x; i < NBINS; i += 256)
        hist_t[i * NB1 + b] = h[i];     // bin-major for the per-bin scan
}

__global__ __launch_bounds__(256) void p1_scanbins_k(int* __restrict__ hist_t,
                                                     int* __restrict__ bintot) {
    __shared__ int sd[256];
    __shared__ int carry;
    int bin = blockIdx.x, t = threadIdx.x;
    if (t == 0) carry = 0;
    __syncthreads();
    int* row = hist_t + bin * NB1;
    for (int base = 0; base < NB1; base += 256) {
        int v = row[base + t];
        sd[t] = v; __syncthreads();
        for (int o = 1; o < 256; o <<= 1) {
            int x = (t >= o) ? sd[t - o] : 0;
            __syncthreads();
            sd[t] += x;
            __syncthreads();
        }
        row[base + t] = carry + sd[t] - v;   // exclusive within bin
        __syncthreads();
        if (t == 255) carry += sd[255];
        __syncthreads();
    }
    if (t == 0) bintot[bin] = carry;
}

__global__ __launch_bounds__(1024) void binstart_k(const int* __restrict__ bintot,
                                                   int* __restrict__ binstart,
                                                   int* __restrict__ rowptr) {
    __shared__ int sd[1024];
    int t = threadIdx.x;
    int v = (t < NBINS) ? bintot[t] : 0;
    sd[t] = v; __syncthreads();
    for (int o = 1; o < 1024; o <<= 1) {
        int x = (t >= o) ? sd[t - o] : 0;
        __syncthreads();
        sd[t] += x;
        __syncthreads();
    }
    if (t < NBINS) binstart[t] = sd[t] - v;
    if (t == 0) { binstart[NBINS] = EDGES_E; rowptr[NODES_N] = EDGES_E; }
}

// phase 1d: scatter packed (src<<8 | dst&255) into bin regions; cursors in LDS
__global__ __launch_bounds__(256) void p1_scatter_k(const int* __restrict__ src,
                                                    const int* __restrict__ dst,
                                                    const int* __restrict__ hist_t,
                                                    const int* __restrict__ binstart,
                                                    uint* __restrict__ pairs) {
    __shared__ int cur[NBINS];
    int b = blockIdx.x;
    for (int i = threadIdx.x; i < NBINS; i += 256)
        cur[i] = binstart[i] + hist_t[i * NB1 + b];
    __syncthreads();
    int e0 = b * EPB1, e1 = min(EDGES_E, e0 + EPB1);
    for (int e = e0 + threadIdx.x; e < e1; e += 256) {
        int d = dst[e];
        int pos = atomicAdd(&cur[d >> BIN_SHIFT], 1);
        pairs[pos] = ((uint)src[e] << BIN_SHIFT) | (uint)(d & (BIN_NODES - 1));
    }
}

// phase 2: per bin (256 nodes), build CSR rowptr/colidx + dinv + scaled bf16 x~
__global__ __launch_bounds__(256) void p2_build_k(const uint* __restrict__ pairs,
                                                  const int* __restrict__ binstart,
                                                  const float* __restrict__ x,
                                                  int* __restrict__ colidx,
                                                  int* __restrict__ rowptr,
                                                  float* __restrict__ dinv,
                                                  uint* __restrict__ xt) {
    __shared__ int h[BIN_NODES];
    __shared__ int off[BIN_NODES];
    __shared__ int cur[BIN_NODES];
    __shared__ float ldv[BIN_NODES];
    int bin = blockIdx.x, t = threadIdx.x;
    int node0 = bin << BIN_SHIFT;
    h[t] = 0;
    __syncthreads();
    int e0 = binstart[bin], e1 = binstart[bin + 1];
    for (int e = e0 + t; e < e1; e += 256)
        atomicAdd(&h[pairs[e] & (BIN_NODES - 1)], 1);
    __syncthreads();
    off[t] = h[t];
    __syncthreads();
    for (int o = 1; o < BIN_NODES; o <<= 1) {
        int x2 = (t >= o) ? off[t - o] : 0;
        __syncthreads();
        off[t] += x2;
        __syncthreads();
    }
    {
        int excl = off[t] - h[t];
        cur[t] = e0 + excl;
        float dv = rsqrtf((float)h[t] + 1.0f);
        ldv[t] = dv;
        int node = node0 + t;
        if (node < NODES_N) {
            rowptr[node] = e0 + excl;
            dinv[node] = dv;
        }
    }
    __syncthreads();
    for (int e = e0 + t; e < e1; e += 256) {
        uint p = pairs[e];
        int pos = atomicAdd(&cur[p & (BIN_NODES - 1)], 1);
        colidx[pos] = (int)(p >> BIN_SHIFT);
    }
    // fused scale_x: x~ = bf16(x * dinv) for this bin's nodes
    int nmax = min(NODES_N - node0, BIN_NODES);
    for (int i = t; i < nmax * 16; i += 256) {
        int nl = i >> 4, c = i & 15;
        int node = node0 + nl;
        float dv = ldv[nl];
        float4 v = *(const float4*)&x[(size_t)node * 64 + c * 4];
        uint2 o = make_uint2(pack_bf2(v.x * dv, v.y * dv), pack_bf2(v.z * dv, v.w * dv));
        *(uint2*)&xt[(size_t)node * 32 + c * 2] = o;
    }
}

// ---------------- gather 64-dim bf16 -> bf16 sum (unroll-8) ----------------

__global__ __launch_bounds__(256) void gather64_k(const uint* __restrict__ xt,
                                                  const int* __restrict__ rowptr,
                                                  const int* __restrict__ colidx,
                                                  uint* __restrict__ st, int n) {
    int lane = threadIdx.x & 7;
    int local = threadIdx.x >> 3;   // 32 nodes/block
    int co = lane * 4;
    int node = blockIdx.x * 32 + local;
    if (node >= n) return;
    float a0=0,a1=0,a2=0,a3=0,a4=0,a5=0,a6=0,a7=0;
    uint4 v = *(const uint4*)&xt[(size_t)node * 32 + co];
    acc_bf2(v.x, a0, a1); acc_bf2(v.y, a2, a3);
    acc_bf2(v.z, a4, a5); acc_bf2(v.w, a6, a7);
    int beg = rowptr[node], end = rowptr[node + 1];
    int e = beg;
    for (; e + 7 < end; e += 8) {
        int i0 = colidx[e],   i1 = colidx[e+1], i2 = colidx[e+2], i3 = colidx[e+3];
        int i4 = colidx[e+4], i5 = colidx[e+5], i6 = colidx[e+6], i7 = colidx[e+7];
        uint4 w0 = *(const uint4*)&xt[(size_t)i0 * 32 + co];
        uint4 w1 = *(const uint4*)&xt[(size_t)i1 * 32 + co];
        uint4 w2 = *(const uint4*)&xt[(size_t)i2 * 32 + co];
        uint4 w3 = *(const uint4*)&xt[(size_t)i3 * 32 + co];
        uint4 w4 = *(const uint4*)&xt[(size_t)i4 * 32 + co];
        uint4 w5 = *(const uint4*)&xt[(size_t)i5 * 32 + co];
        uint4 w6 = *(const uint4*)&xt[(size_t)i6 * 32 + co];
        uint4 w7 = *(const uint4*)&xt[(size_t)i7 * 32 + co];
        acc_bf2(w0.x,a0,a1); acc_bf2(w0.y,a2,a3); acc_bf2(w0.z,a4,a5); acc_bf2(w0.w,a6,a7);
        acc_bf2(w1.x,a0,a1); acc_bf2(w1.y,a2,a3); acc_bf2(w1.z,a4,a5); acc_bf2(w1.w,a6,a7);
        acc_bf2(w2.x,a0,a1); acc_bf2(w2.y,a2,a3); acc_bf2(w2.z,a4,a5); acc_bf2(w2.w,a6,a7);
        acc_bf2(w3.x,a0,a1); acc_bf2(w3.y,a2,a3); acc_bf2(w3.z,a4,a5); acc_bf2(w3.w,a6,a7);
        acc_bf2(w4.x,a0,a1); acc_bf2(w4.y,a2,a3); acc_bf2(w4.z,a4,a5); acc_bf2(w4.w,a6,a7);
        acc_bf2(w5.x,a0,a1); acc_bf2(w5.y,a2,a3); acc_bf2(w5.z,a4,a5); acc_bf2(w5.w,a6,a7);
        acc_bf2(w6.x,a0,a1); acc_bf2(w6.y,a2,a3); acc_bf2(w6.z,a4,a5); acc_bf2(w6.w,a6,a7);
        acc_bf2(w7.x,a0,a1); acc_bf2(w7.y,a2,a3); acc_bf2(w7.z,a4,a5); acc_bf2(w7.w,a6,a7);
    }
    for (; e + 3 < end; e += 4) {
        int i0 = colidx[e], i1 = colidx[e+1], i2 = colidx[e+2], i3 = colidx[e+3];
        uint4 w0 = *(const uint4*)&xt[(size_t)i0 * 32 + co];
        uint4 w1 = *(const uint4*)&xt[(size_t)i1 * 32 + co];
        uint4 w2 = *(const uint4*)&xt[(size_t)i2 * 32 + co];
        uint4 w3 = *(const uint4*)&xt[(size_t)i3 * 32 + co];
        acc_bf2(w0.x,a0,a1); acc_bf2(w0.y,a2,a3); acc_bf2(w0.z,a4,a5); acc_bf2(w0.w,a6,a7);
        acc_bf2(w1.x,a0,a1); acc_bf2(w1.y,a2,a3); acc_bf2(w1.z,a4,a5); acc_bf2(w1.w,a6,a7);
        acc_bf2(w2.x,a0,a1); acc_bf2(w2.y,a2,a3); acc_bf2(w2.z,a4,a5); acc_bf2(w2.w,a6,a7);
        acc_bf2(w3.x,a0,a1); acc_bf2(w3.y,a2,a3); acc_bf2(w3.z,a4,a5); acc_bf2(w3.w,a6,a7);
    }
    for (; e < end; e++) {
        uint4 w0 = *(const uint4*)&xt[(size_t)colidx[e] * 32 + co];
        acc_bf2(w0.x,a0,a1); acc_bf2(w0.y,a2,a3); acc_bf2(w0.z,a4,a5); acc_bf2(w0.w,a6,a7);
    }
    uint4 o;
    o.x = pack_bf2(a0, a1);
    o.y = pack_bf2(a2, a3);
    o.z = pack_bf2(a4, a5);
    o.w = pack_bf2(a6, a7);
    *(uint4*)&st[(size_t)node * 32 + co] = o;
}

// ---------------- dual MFMA GEMM: h2' = bf16( dinv * ( relu(dinv*(s~@W1)+b1) @ W2 ) ) ----------------
// C/D layout (HW-verified): col = lane&15, row = (lane>>4)*4 + reg.

__global__ __launch_bounds__(256) void gemm_dual_k(const ushort* __restrict__ A,
                                                   const ushort* __restrict__ W1f,
                                                   const ushort* __restrict__ W2f,
                                                   const float* __restrict__ dinv,
                                                   const float* __restrict__ b1,
                                                   ushort* __restrict__ h2p, int n) {
    __shared__ ushort hl[4][16][132];
    int wave = threadIdx.x >> 6;
    int lane = threadIdx.x & 63;
    int row0 = (blockIdx.x * 4 + wave) * 16;
    if (row0 >= n) return;
    int m = lane & 15, g = lane >> 4;
    int arow = min(row0 + m, n - 1);

    // GEMM1: K=64
    const ushort* ab = &A[(size_t)arow * 64 + g * 8];
    bf16x8 a0 = *reinterpret_cast<const bf16x8*>(ab);
    bf16x8 a1 = *reinterpret_cast<const bf16x8*>(ab + 32);
    f32x4 acc[8];
#pragma unroll
    for (int nt = 0; nt < 8; nt++) {
        acc[nt] = (f32x4){0.f, 0.f, 0.f, 0.f};
        bf16x8 w0 = *reinterpret_cast<const bf16x8*>(&W1f[((size_t)(nt * 2 + 0) * 64 + lane) * 8]);
        bf16x8 w1 = *reinterpret_cast<const bf16x8*>(&W1f[((size_t)(nt * 2 + 1) * 64 + lane) * 8]);
        acc[nt] = __builtin_amdgcn_mfma_f32_16x16x32_bf16(a0, w0, acc[nt], 0, 0, 0);
        acc[nt] = __builtin_amdgcn_mfma_f32_16x16x32_bf16(a1, w1, acc[nt], 0, 0, 0);
    }

    // epilogue 1 -> LDS (transposed store: [row][channel])
    int orow0 = row0 + g * 4;
#pragma unroll
    for (int r = 0; r < 4; r++) {
        float dvr = dinv[min(orow0 + r, n - 1)];
#pragma unroll
        for (int nt = 0; nt < 8; nt++) {
            float v = fmaxf(fmaf(dvr, acc[nt][r], b1[nt * 16 + m]), 0.f);
            hl[wave][g * 4 + r][nt * 16 + m] = f2bf(v);
        }
    }

    // A-fragments for K=128 from LDS
    bf16x8 hfrag[4];
#pragma unroll
    for (int ks = 0; ks < 4; ks++) {
        uint2 lo = *(const uint2*)&hl[wave][m][g * 8 + ks * 32];
        uint2 hi = *(const uint2*)&hl[wave][m][g * 8 + ks * 32 + 4];
        uint4 u = make_uint4(lo.x, lo.y, hi.x, hi.y);
        hfrag[ks] = *reinterpret_cast<bf16x8*>(&u);
    }

    // GEMM2: K=128
    f32x4 acc2[8];
#pragma unroll
    for (int nt = 0; nt < 8; nt++) {
        acc2[nt] = (f32x4){0.f, 0.f, 0.f, 0.f};
#pragma unroll
        for (int ks = 0; ks < 4; ks++) {
            bf16x8 w = *reinterpret_cast<const bf16x8*>(&W2f[((size_t)(nt * 4 + ks) * 64 + lane) * 8]);
            acc2[nt] = __builtin_amdgcn_mfma_f32_16x16x32_bf16(hfrag[ks], w, acc2[nt], 0, 0, 0);
        }
    }

    // epilogue 2: h2' = bf16(dinv * acc2)
#pragma unroll
    for (int r = 0; r < 4; r++) {
        int row = orow0 + r;
        if (row < n) {
            float dvr = dinv[row];
#pragma unroll
            for (int nt = 0; nt < 8; nt++)
                h2p[(size_t)row * 128 + nt * 16 + m] = f2bf(acc2[nt][r] * dvr);
        }
    }
}

// ---------------- gather 128-dim, channel-half pass P=blockIdx.y (unroll-8) ----------------

__global__ __launch_bounds__(256) void gather128_k(const uint* __restrict__ hp,
                                                   const int* __restrict__ rowptr,
                                                   const int* __restrict__ colidx,
                                                   const float* __restrict__ dinv,
                                                   const float* __restrict__ bias,
                                                   uint* __restrict__ h2b, int n) {
    int P = blockIdx.y;
    int lane = threadIdx.x & 7;
    int local = threadIdx.x >> 3;   // 32 nodes/block
    int co = P * 32 + lane * 4;     // uint offset in row of 64 uints
    int node = blockIdx.x * 32 + local;
    if (node >= n) return;
    float a0=0,a1=0,a2=0,a3=0,a4=0,a5=0,a6=0,a7=0;
    uint4 v = *(const uint4*)&hp[(size_t)node * 64 + co];
    acc_bf2(v.x, a0, a1); acc_bf2(v.y, a2, a3);
    acc_bf2(v.z, a4, a5); acc_bf2(v.w, a6, a7);
    int beg = rowptr[node], end = rowptr[node + 1];
    int e = beg;
    for (; e + 7 < end; e += 8) {
        int i0 = colidx[e],   i1 = colidx[e+1], i2 = colidx[e+2], i3 = colidx[e+3];
        int i4 = colidx[e+4], i5 = colidx[e+5], i6 = colidx[e+6], i7 = colidx[e+7];
        uint4 w0 = *(const uint4*)&hp[(size_t)i0 * 64 + co];
        uint4 w1 = *(const uint4*)&hp[(size_t)i1 * 64 + co];
        uint4 w2 = *(const uint4*)&hp[(size_t)i2 * 64 + co];
        uint4 w3 = *(const uint4*)&hp[(size_t)i3 * 64 + co];
        uint4 w4 = *(const uint4*)&hp[(size_t)i4 * 64 + co];
        uint4 w5 = *(const uint4*)&hp[(size_t)i5 * 64 + co];
        uint4 w6 = *(const uint4*)&hp[(size_t)i6 * 64 + co];
        uint4 w7 = *(const uint4*)&hp[(size_t)i7 * 64 + co];
        acc_bf2(w0.x,a0,a1); acc_bf2(w0.y,a2,a3); acc_bf2(w0.z,a4,a5); acc_bf2(w0.w,a6,a7);
        acc_bf2(w1.x,a0,a1); acc_bf2(w1.y,a2,a3); acc_bf2(w1.z,a4,a5); acc_bf2(w1.w,a6,a7);
        acc_bf2(w2.x,a0,a1); acc_bf2(w2.y,a2,a3); acc_bf2(w2.z,a4,a5); acc_bf2(w2.w,a6,a7);
        acc_bf2(w3.x,a0,a1); acc_bf2(w3.y,a2,a3); acc_bf2(w3.z,a4,a5); acc_bf2(w3.w,a6,a7);
        acc_bf2(w4.x,a0,a1); acc_bf2(w4.y,a2,a3); acc_bf2(w4.z,a4,a5); acc_bf2(w4.w,a6,a7);
        acc_bf2(w5.x,a0,a1); acc_bf2(w5.y,a2,a3); acc_bf2(w5.z,a4,a5); acc_bf2(w5.w,a6,a7);
        acc_bf2(w6.x,a0,a1); acc_bf2(w6.y,a2,a3); acc_bf2(w6.z,a4,a5); acc_bf2(w6.w,a6,a7);
        acc_bf2(w7.x,a0,a1); acc_bf2(w7.y,a2,a3); acc_bf2(w7.z,a4,a5); acc_bf2(w7.w,a6,a7);
    }
    for (; e + 3 < end; e += 4) {
        int i0 = colidx[e], i1 = colidx[e+1], i2 = colidx[e+2], i3 = colidx[e+3];
        uint4 w0 = *(const uint4*)&hp[(size_t)i0 * 64 + co];
        uint4 w1 = *(const uint4*)&hp[(size_t)i1 * 64 + co];
        uint4 w2 = *(const uint4*)&hp[(size_t)i2 * 64 + co];
        uint4 w3 = *(const uint4*)&hp[(size_t)i3 * 64 + co];
        acc_bf2(w0.x,a0,a1); acc_bf2(w0.y,a2,a3); acc_bf2(w0.z,a4,a5); acc_bf2(w0.w,a6,a7);
        acc_bf2(w1.x,a0,a1); acc_bf2(w1.y,a2,a3); acc_bf2(w1.z,a4,a5); acc_bf2(w1.w,a6,a7);
        acc_bf2(w2.x,a0,a1); acc_bf2(w2.y,a2,a3); acc_bf2(w2.z,a4,a5); acc_bf2(w2.w,a6,a7);
        acc_bf2(w3.x,a0,a1); acc_bf2(w3.y,a2,a3); acc_bf2(w3.z,a4,a5); acc_bf2(w3.w,a6,a7);
    }
    for (; e < end; e++) {
        uint4 w0 = *(const uint4*)&hp[(size_t)colidx[e] * 64 + co];
        acc_bf2(w0.x,a0,a1); acc_bf2(w0.y,a2,a3); acc_bf2(w0.z,a4,a5); acc_bf2(w0.w,a6,a7);
    }
    float dv = dinv[node];
    int jb = P * 64 + lane * 8;
    float4 b0 = *(const float4*)&bias[jb];
    float4 b1 = *(const float4*)&bias[jb + 4];
    float o0 = fmaxf(fmaf(dv, a0, b0.x), 0.f);
    float o1 = fmaxf(fmaf(dv, a1, b0.y), 0.f);
    float o2 = fmaxf(fmaf(dv, a2, b0.z), 0.f);
    float o3 = fmaxf(fmaf(dv, a3, b0.w), 0.f);
    float o4 = fmaxf(fmaf(dv, a4, b1.x), 0.f);
    float o5 = fmaxf(fmaf(dv, a5, b1.y), 0.f);
    float o6 = fmaxf(fmaf(dv, a6, b1.z), 0.f);
    float o7 = fmaxf(fmaf(dv, a7, b1.w), 0.f);
    uint4 ov;
    ov.x = pack_bf2(o0, o1);
    ov.y = pack_bf2(o2, o3);
    ov.z = pack_bf2(o4, o5);
    ov.w = pack_bf2(o6, o7);
    *(uint4*)&h2b[(size_t)node * 64 + co] = ov;
}

// ---------------- pool (bf16 input) ----------------

__global__ __launch_bounds__(128) void pool_k(const uint* __restrict__ h2b,
                                              const int* __restrict__ batch, int n,
                                              float* __restrict__ sums, float* __restrict__ cnts) {
    int j = threadIdx.x;             // channel 0..127
    int wj = j >> 1;                 // uint word
    int hi = j & 1;
    int chunk = (n + gridDim.x - 1) / gridDim.x;
    int i0 = blockIdx.x * chunk;
    int i1 = min(n, i0 + chunk);
    if (i0 >= n) return;
    int cur = batch[i0];
    float acc = 0.f;
    int cnt = 0;
    for (int i = i0; i < i1; i++) {
        int g = batch[i];
        if (g != cur) {
            atomicAdd(&sums[cur * 128 + j], acc);
            if (j == 0) atomicAdd(&cnts[cur], (float)cnt);
            acc = 0.f; cnt = 0; cur = g;
        }
        uint w = h2b[(size_t)i * 64 + wj];
        acc += __uint_as_float(hi ? (w & 0xffff0000u) : (w << 16));
        cnt++;
    }
    atomicAdd(&sums[cur * 128 + j], acc);
    if (j == 0) atomicAdd(&cnts[cur], (float)cnt);
}

// ---------------- MLP head ----------------

__global__ __launch_bounds__(64) void mlp_k(const float* __restrict__ sums, const float* __restrict__ cnts,
                                            const float* __restrict__ Wl1, const float* __restrict__ bl1,
                                            const float* __restrict__ Wl2, const float* __restrict__ bl2,
                                            float* __restrict__ out) {
    __shared__ float pooled[128];
    __shared__ float hidden[64];
    int g = blockIdx.x, t = threadIdx.x;
    float c = fmaxf(cnts[g], 1.0f);
    pooled[t]      = sums[g * 128 + t] / c;
    pooled[t + 64] = sums[g * 128 + 64 + t] / c;
    __syncthreads();
    float a = bl1[t];
#pragma unroll 4
    for (int cc = 0; cc < 128; cc++) a = fmaf(pooled[cc], Wl1[cc * 64 + t], a);
    hidden[t] = fmaxf(a, 0.f);
    __syncthreads();
    if (t < 10) {
        float o = bl2[t];
#pragma unroll 8
        for (int jj = 0; jj < 64; jj++) o = fmaf(hidden[jj], Wl2[jj * 10 + t], o);
        out[g * 10 + t] = o;
    }
}

// ---------------- launch ----------------

extern "C" void kernel_launch(void* const* d_in, const int* in_sizes, int n_in,
                              void* d_out, int out_size, void* d_ws, size_t ws_size,
                              hipStream_t stream) {
    const float* x    = (const float*)d_in[0];
    const int*   src  = (const int*)d_in[1];
    const int*   dst  = (const int*)d_in[2];
    const int*   batch= (const int*)d_in[3];
    const float* W1   = (const float*)d_in[4];
    const float* b1   = (const float*)d_in[5];
    const float* W2   = (const float*)d_in[6];
    const float* b2   = (const float*)d_in[7];
    const float* Wl1  = (const float*)d_in[8];
    const float* bl1  = (const float*)d_in[9];
    const float* Wl2  = (const float*)d_in[10];
    const float* bl2  = (const float*)d_in[11];
    float* out = (float*)d_out;

    const int N = NODES_N;

    size_t off = 0;
    auto take = [&](size_t bytes) { size_t o = off; off = (off + bytes + 255) & ~(size_t)255; return o; };
    char* ws = (char*)d_ws;
    uint*   h2p  = (uint*)(ws + take((size_t)N * 128 * 2));     // h2' bf16 [N,128] as uint[N,64]
    uint*   h2b  = (uint*)(ws + take((size_t)N * 128 * 2));     // h2 bf16 [N,128] as uint[N,64]
    // pairs (4B packed) and s~ (gather64 output) never coexist: share a 12.8 MB region
    size_t  shbytes = (size_t)N * 64 * 2;                       // 12.8 MB >= E*4 (6.4 MB)
    char*   shreg = ws + take(shbytes);
    uint*   pairs = (uint*)shreg;
    uint*   stil  = (uint*)shreg;                               // s~ bf16 [N,64] as uint[N,32]
    uint*   xt   = (uint*)(ws + take((size_t)N * 64 * 2));      // x~ bf16 [N,64]
    float*  dinv = (float*)(ws + take((size_t)N * 4));
    ushort* W1f  = (ushort*)(ws + take((size_t)64 * 128 * 2));
    ushort* W2f  = (ushort*)(ws + take((size_t)128 * 128 * 2));
    size_t zbytes = (size_t)NZERO * 4;
    char*  zbase  = ws + take(zbytes);
    float* sums   = (float*)zbase;
    float* cnts   = (float*)(zbase + (size_t)GRAPHS_G * 128 * 4);
    int*   rowptr = (int*)(ws + take((size_t)(N + 1) * 4));
    int*   colidx = (int*)(ws + take((size_t)EDGES_E * 4));
    int*   hist_t = (int*)(ws + take((size_t)NBINS * NB1 * 4));
    int*   bintot = (int*)(ws + take((size_t)NBINS * 4));
    int*   binstart = (int*)(ws + take((size_t)(NBINS + 1) * 4));
    (void)ws_size; (void)in_sizes; (void)n_in; (void)out_size;

    // CSR critical chain first; independent pack/zero kernel fills its bubble
    p1_hist_k<<<NB1, 256, 0, stream>>>(dst, hist_t);
    pack_w_zero_k<<<(24576 + NZERO + 255) / 256, 256, 0, stream>>>(W1, W1f, W2, W2f, sums);
    p1_scanbins_k<<<NBINS, 256, 0, stream>>>(hist_t, bintot);
    binstart_k<<<1, 1024, 0, stream>>>(bintot, binstart, rowptr);
    p1_scatter_k<<<NB1, 256, 0, stream>>>(src, dst, hist_t, binstart, pairs);
    p2_build_k<<<NBINS, 256, 0, stream>>>(pairs, binstart, x, colidx, rowptr, dinv, xt);

    // conv1 gather: s~ = xt[self] + sum xt[src]
    int g32 = (N + 31) / 32;
    gather64_k<<<g32, 256, 0, stream>>>(xt, rowptr, colidx, stil, N);

    // dual GEMM: h1 stays on-chip; h2' = bf16(dinv*(relu(dinv*(s~@W1)+b1)@W2))
    int gblk = (N + 63) / 64;
    gemm_dual_k<<<gblk, 256, 0, stream>>>((const ushort*)stil, W1f, W2f, dinv, b1, (ushort*)h2p, N);

    // conv2 gather: h2 = bf16(relu(dinv*(self+sum) + b2)), two channel-half passes in one launch
    gather128_k<<<dim3(g32, 2), 256, 0, stream>>>(h2p, rowptr, colidx, dinv, b2, h2b, N);

    // pool + head
    pool_k<<<1024, 128, 0, stream>>>(h2b, batch, N, sums, cnts);
    mlp_k<<<GRAPHS_G, 64, 0, stream>>>(sums, cnts, Wl1, bl1, Wl2, bl2, out);
}